// Round 6
// baseline (578.281 us; speedup 1.0000x reference)
//
#include <hip/hip_runtime.h>
#include <math.h>

// predicted/target: (B,T,H,W,1) fp32
#define BB 8
#define TT 16
#define HH 256
#define WW 256
#define NPX (TT * HH * WW)      // 1,048,576 px per sample
#define CROWS 32                // output rows per ssim block
#define NBLK (BB * TT * (HH / CROWS)) // 1024 ssim blocks

// ws float layout (512 = 8 samples x 64 chunks)
#define P_MINP 0
#define P_MAXP 512
#define P_MINT 1024
#define P_MAXT 1536
#define P_SUMT 2048
#define WS_S   2560   // accumulated valid-weighted ssim sum
#define WS_CNT 2561   // unsigned ticket counter (last ssim block computes loss)

typedef float v2f __attribute__((ext_vector_type(2)));

// Gaussian taps (exp(-(i-5)^2/4.5), normalized) as literals.
#define G0 0.0010283776f
#define G1 0.0075987582f
#define G2 0.0360008014f
#define G3 0.1093606427f
#define G4 0.2130055745f
#define G5 0.2660117857f
#define GA_(k) ((k) == 0 || (k) == 10 ? G0 : (k) == 1 || (k) == 9 ? G1 \
              : (k) == 2 || (k) == 8 ? G2 : (k) == 3 || (k) == 7 ? G3 \
              : (k) == 4 || (k) == 6 ? G4 : G5)

// Per-sample min/max of pred & targ + sum(targ), one partial per block.
__global__ __launch_bounds__(256) void k_reduce(const float* __restrict__ p,
                                                const float* __restrict__ t,
                                                float* __restrict__ wsf) {
  const int b = blockIdx.x >> 6;
  const size_t base = (size_t)b * NPX + (size_t)(blockIdx.x & 63) * (NPX / 64);
  const int tid = threadIdx.x;

  float mnp = 3.4e38f, mxp = -3.4e38f, mnt = 3.4e38f, mxt = -3.4e38f, st = 0.f;
  const float4* p4 = (const float4*)(p + base);
  const float4* t4 = (const float4*)(t + base);
#pragma unroll 4
  for (int it = 0; it < 16; ++it) {
    float4 a = p4[it * 256 + tid];
    float4 c = t4[it * 256 + tid];
    mnp = fminf(mnp, fminf(fminf(a.x, a.y), fminf(a.z, a.w)));
    mxp = fmaxf(mxp, fmaxf(fmaxf(a.x, a.y), fmaxf(a.z, a.w)));
    mnt = fminf(mnt, fminf(fminf(c.x, c.y), fminf(c.z, c.w)));
    mxt = fmaxf(mxt, fmaxf(fmaxf(c.x, c.y), fmaxf(c.z, c.w)));
    st += c.x + c.y + c.z + c.w;
  }
  for (int off = 32; off > 0; off >>= 1) {
    mnp = fminf(mnp, __shfl_down(mnp, off));
    mxp = fmaxf(mxp, __shfl_down(mxp, off));
    mnt = fminf(mnt, __shfl_down(mnt, off));
    mxt = fmaxf(mxt, __shfl_down(mxt, off));
    st += __shfl_down(st, off);
  }
  __shared__ float s_mnp[4], s_mxp[4], s_mnt[4], s_mxt[4], s_st[4];
  int wave = tid >> 6, lane = tid & 63;
  if (lane == 0) {
    s_mnp[wave] = mnp; s_mxp[wave] = mxp;
    s_mnt[wave] = mnt; s_mxt[wave] = mxt; s_st[wave] = st;
  }
  __syncthreads();
  if (tid == 0) {
    for (int w = 1; w < 4; ++w) {
      mnp = fminf(mnp, s_mnp[w]); mxp = fmaxf(mxp, s_mxp[w]);
      mnt = fminf(mnt, s_mnt[w]); mxt = fmaxf(mxt, s_mxt[w]);
      st += s_st[w];
    }
    wsf[P_MINP + blockIdx.x] = mnp;
    wsf[P_MAXP + blockIdx.x] = mxp;
    wsf[P_MINT + blockIdx.x] = mnt;
    wsf[P_MAXT + blockIdx.x] = mxt;
    wsf[P_SUMT + blockIdx.x] = st;
    if (blockIdx.x == 0) {
      wsf[WS_S] = 0.f;
      ((unsigned int*)wsf)[WS_CNT] = 0u;
    }
  }
}

// One row-step. Wave-private LDS staging: each wave stages 74 cols (64 own +
// 10 redundant halo) into its own double-buffered segment -> NO __syncthreads
// in the main loop. Waves run self-paced; prefetch loads stay in flight
// across steps (no barrier-forced vmcnt(0) drain). J literal -> buffer
// parity, ring slot, output guard compile-time; ring stays in VGPRs.
#define STEP(J) do {                                                         \
    constexpr int jj = (J);                                                  \
    constexpr int buf = jj & 1;                                              \
    constexpr int slot = jj % 11;                                            \
    const bool in = (unsigned)(ystart + jj) < (unsigned)HH;                  \
    const bool v0 = in && c0ok, v1 = in && c1ok;                             \
    v2f nv0, nv1;                                                            \
    nv0.x = v0 ? fmaf(tcur0, ts, tb) : 0.f;                                  \
    nv0.y = v0 ? fmaf(pcur0, ps, pb) : 0.f;                                  \
    nv1.x = v1 ? fmaf(tcur1, ts, tb) : 0.f;                                  \
    nv1.y = v1 ? fmaf(pcur1, ps, pb) : 0.f;                                  \
    sstage[wid][buf][lane] = nv0;                                            \
    if (lane < 10) sstage[wid][buf][64 + lane] = nv1;                        \
    if constexpr (jj < 41) {                                                 \
      const int yn = min(max(ystart + jj + 1, 0), HH - 1);                   \
      tnxt0 = tptr[(size_t)yn * WW + col0c];                                 \
      pnxt0 = pptr[(size_t)yn * WW + col0c];                                 \
      if (lane < 10) {                                                       \
        tnxt1 = tptr[(size_t)yn * WW + col1c];                               \
        pnxt1 = pptr[(size_t)yn * WW + col1c];                               \
      }                                                                      \
    }                                                                        \
    v2f hmu = {0.f, 0.f}, hsq = {0.f, 0.f};                                  \
    float htp = 0.f;                                                         \
    _Pragma("unroll")                                                        \
    for (int k = 0; k < 11; ++k) {                                           \
      v2f v = sstage[wid][buf][lane + k];                                    \
      v2f g2 = {GA_(k), GA_(k)};                                             \
      v2f w = g2 * v;                                                        \
      hmu = hmu + w;                                                         \
      hsq = __builtin_elementwise_fma(w, v, hsq);                            \
      htp = fmaf(w.x, v.y, htp);                                             \
    }                                                                        \
    r_mu[slot] = hmu; r_sq[slot] = hsq; r_tp[slot] = htp;                    \
    if constexpr (jj >= 10) {                                                \
      v2f vmu = {0.f, 0.f}, vsq = {0.f, 0.f};                                \
      float vtp = 0.f;                                                       \
      _Pragma("unroll")                                                      \
      for (int k = 0; k < 11; ++k) {                                         \
        const int s = (jj + 1 + k) % 11;                                     \
        v2f g2 = {GA_(k), GA_(k)};                                           \
        vmu = __builtin_elementwise_fma(g2, r_mu[s], vmu);                   \
        vsq = __builtin_elementwise_fma(g2, r_sq[s], vsq);                   \
        vtp = fmaf(GA_(k), r_tp[s], vtp);                                    \
      }                                                                      \
      float m1 = vmu.x, m2 = vmu.y;                                          \
      float mu11 = m1 * m1, mu22 = m2 * m2, m12 = m1 * m2;                   \
      float s1 = fmaxf(vsq.x - mu11, 1e-6f);                                 \
      float s2 = fmaxf(vsq.y - mu22, 1e-6f);                                 \
      float s12 = vtp - m12;                                                 \
      float root = sqrtf(s1 * s2);                                           \
      float num = fmaf(2.f, m12, C1) * fmaf(2.f, root, C2) * (s12 + C3);     \
      float den = (mu11 + mu22 + C1) * (s1 + s2 + C2) * (root + C3);         \
      acc = fmaf(num, __builtin_amdgcn_rcpf(den), acc);                      \
    }                                                                        \
    tcur0 = tnxt0; pcur0 = pnxt0; tcur1 = tnxt1; pcur1 = pnxt1;              \
    __builtin_amdgcn_sched_barrier(0);                                       \
  } while (0)

__global__ __launch_bounds__(256, 4) void k_ssim(const float* __restrict__ pred,
                                                 const float* __restrict__ targ,
                                                 float* __restrict__ wsf,
                                                 float* __restrict__ out) {
  const int img = blockIdx.x >> 3;    // 0..127
  const int chunk = blockIdx.x & 7;   // 0..7
  const int b = img >> 4;             // sample
  const int x = threadIdx.x;
  const int wid = x >> 6, lane = x & 63;
  const int y0 = chunk * CROWS;
  const float* tptr = targ + (size_t)img * (HH * WW);
  const float* pptr = pred + (size_t)img * (HH * WW);

  // Preamble: reduce this sample's 64 partials -> norm params + valid (wave 0)
  __shared__ float sprm[5];  // ps, pb, ts, tb, valid
  if (x < 64) {
    float mnp = wsf[P_MINP + b * 64 + x];
    float mxp = wsf[P_MAXP + b * 64 + x];
    float mnt = wsf[P_MINT + b * 64 + x];
    float mxt = wsf[P_MAXT + b * 64 + x];
    float st  = wsf[P_SUMT + b * 64 + x];
    for (int off = 32; off > 0; off >>= 1) {
      mnp = fminf(mnp, __shfl_down(mnp, off));
      mxp = fmaxf(mxp, __shfl_down(mxp, off));
      mnt = fminf(mnt, __shfl_down(mnt, off));
      mxt = fmaxf(mxt, __shfl_down(mxt, off));
      st += __shfl_down(st, off);
    }
    if (x == 0) {
      float psv = 1.f / fmaxf(mxp - mnp, 1e-6f);
      float tsv = 1.f / fmaxf(mxt - mnt, 1e-6f);
      sprm[0] = psv; sprm[1] = -mnp * psv;
      sprm[2] = tsv; sprm[3] = -mnt * tsv;
      sprm[4] = (st != 0.f) ? 1.f : 0.f;
    }
  }

  // Wave-private double-buffered staging: 74 cols of (t,p) per wave.
  __shared__ v2f sstage[4][2][74];
  __syncthreads();  // sprm ready — the ONLY block barrier before the epilogue
  const float ps = sprm[0], pb = sprm[1], ts = sprm[2], tb = sprm[3];

  // Column mapping: position q in [0,74) <-> image col wid*64 - 5 + q.
  // Lane writes position `lane` (col0) and, for lane<10, position 64+lane
  // (col1). Out-of-image cols produce zeros (x halo).
  const int col0 = wid * 64 - 5 + lane;
  const bool c0ok = col0 >= 0;                 // col0 <= 250 always
  const int col0c = max(col0, 0);
  const int col1 = wid * 64 + 59 + lane;       // meaningful for lane<10
  const bool c1ok = (lane < 10) && (col1 < WW);
  const int col1c = min(col1, WW - 1);

  // Ring: h-conv results for 11 rows; only constant indices -> registers.
  v2f r_mu[11], r_sq[11];
  float r_tp[11];
  float acc = 0.f;
  const int ystart = y0 - 5;  // step j stages row ystart+j; output yo = row-5
  const float C1 = 1e-4f, C2 = 9e-4f, C3 = 4.5e-4f;

  // Prime the 1-step prefetch
  float tcur0, pcur0, tcur1 = 0.f, pcur1 = 0.f;
  float tnxt0 = 0.f, pnxt0 = 0.f, tnxt1 = 0.f, pnxt1 = 0.f;
  {
    const int yc = min(max(ystart, 0), HH - 1);
    tcur0 = tptr[(size_t)yc * WW + col0c];
    pcur0 = pptr[(size_t)yc * WW + col0c];
    if (lane < 10) {
      tcur1 = tptr[(size_t)yc * WW + col1c];
      pcur1 = pptr[(size_t)yc * WW + col1c];
    }
  }

  STEP(0);  STEP(1);  STEP(2);  STEP(3);  STEP(4);  STEP(5);  STEP(6);
  STEP(7);  STEP(8);  STEP(9);  STEP(10); STEP(11); STEP(12); STEP(13);
  STEP(14); STEP(15); STEP(16); STEP(17); STEP(18); STEP(19); STEP(20);
  STEP(21); STEP(22); STEP(23); STEP(24); STEP(25); STEP(26); STEP(27);
  STEP(28); STEP(29); STEP(30); STEP(31); STEP(32); STEP(33); STEP(34);
  STEP(35); STEP(36); STEP(37); STEP(38); STEP(39); STEP(40); STEP(41);

  // Block reduction + valid-weighted accumulate + ticket
  for (int off = 32; off > 0; off >>= 1) acc += __shfl_down(acc, off);
  __shared__ float sred[4];
  __shared__ unsigned int s_last;
  if (lane == 0) sred[wid] = acc;
  __syncthreads();
  if (x == 0) {
    float v = sred[0] + sred[1] + sred[2] + sred[3];
    atomicAdd(&wsf[WS_S], v * sprm[4]);
    __threadfence();  // release: WS_S add visible before ticket bump
    unsigned int old = atomicAdd(((unsigned int*)wsf) + WS_CNT, 1u);
    s_last = (old == (unsigned int)(NBLK - 1)) ? 1u : 0u;
  }
  __syncthreads();

  // Loss epilogue: exactly one block (the last to tick) computes out[0].
  if (s_last && x < 64) {
    float sums[8];
#pragma unroll
    for (int bb = 0; bb < 8; ++bb) sums[bb] = wsf[P_SUMT + bb * 64 + x];
    for (int off = 32; off > 0; off >>= 1) {
#pragma unroll
      for (int bb = 0; bb < 8; ++bb) sums[bb] += __shfl_down(sums[bb], off);
    }
    if (x == 0) {
      __threadfence();  // acquire side of the ticket
      float sv = 0.f;
#pragma unroll
      for (int bb = 0; bb < 8; ++bb) sv += (sums[bb] != 0.f) ? 1.f : 0.f;
      float S = atomicAdd(&wsf[WS_S], 0.f);  // coherent read of final sum
      out[0] = (sv - S * (1.f / (float)NPX)) / fmaxf(sv, 1.f);
    }
  }
}

extern "C" void kernel_launch(void* const* d_in, const int* in_sizes, int n_in,
                              void* d_out, int out_size, void* d_ws, size_t ws_size,
                              hipStream_t stream) {
  const float* pred = (const float*)d_in[0];
  const float* targ = (const float*)d_in[1];
  float* wsf = (float*)d_ws;
  float* out = (float*)d_out;

  hipLaunchKernelGGL(k_reduce, dim3(512), dim3(256), 0, stream, pred, targ, wsf);
  hipLaunchKernelGGL(k_ssim, dim3(NBLK), dim3(256), 0, stream, pred, targ, wsf, out);
}

// Round 7
// 142.934 us; speedup vs baseline: 4.0458x; 4.0458x over previous
//
#include <hip/hip_runtime.h>
#include <math.h>

// predicted/target: (B,T,H,W,1) fp32
#define BB 8
#define TT 16
#define HH 256
#define WW 256
#define NPX (TT * HH * WW)      // 1,048,576 px per sample
#define CROWS 32                // output rows per ssim block
#define NBLK (BB * TT * (HH / CROWS)) // 1024 ssim blocks

// ws float layout (512 = 8 samples x 64 chunks)
#define P_MINP 0
#define P_MAXP 512
#define P_MINT 1024
#define P_MAXT 1536
#define P_SUMT 2048
#define WS_S   2560   // accumulated valid-weighted ssim sum
#define WS_CNT 2561   // unsigned ticket counter (last ssim block computes loss)

typedef float v2f __attribute__((ext_vector_type(2)));

// Gaussian taps (exp(-(i-5)^2/4.5), normalized) as literals.
#define G0 0.0010283776f
#define G1 0.0075987582f
#define G2 0.0360008014f
#define G3 0.1093606427f
#define G4 0.2130055745f
#define G5 0.2660117857f
#define GA_(k) ((k) == 0 || (k) == 10 ? G0 : (k) == 1 || (k) == 9 ? G1 \
              : (k) == 2 || (k) == 8 ? G2 : (k) == 3 || (k) == 7 ? G3 \
              : (k) == 4 || (k) == 6 ? G4 : G5)

// Per-sample min/max of pred & targ + sum(targ), one partial per block.
__global__ __launch_bounds__(256) void k_reduce(const float* __restrict__ p,
                                                const float* __restrict__ t,
                                                float* __restrict__ wsf) {
  const int b = blockIdx.x >> 6;
  const size_t base = (size_t)b * NPX + (size_t)(blockIdx.x & 63) * (NPX / 64);
  const int tid = threadIdx.x;

  float mnp = 3.4e38f, mxp = -3.4e38f, mnt = 3.4e38f, mxt = -3.4e38f, st = 0.f;
  const float4* p4 = (const float4*)(p + base);
  const float4* t4 = (const float4*)(t + base);
#pragma unroll 4
  for (int it = 0; it < 16; ++it) {
    float4 a = p4[it * 256 + tid];
    float4 c = t4[it * 256 + tid];
    mnp = fminf(mnp, fminf(fminf(a.x, a.y), fminf(a.z, a.w)));
    mxp = fmaxf(mxp, fmaxf(fmaxf(a.x, a.y), fmaxf(a.z, a.w)));
    mnt = fminf(mnt, fminf(fminf(c.x, c.y), fminf(c.z, c.w)));
    mxt = fmaxf(mxt, fmaxf(fmaxf(c.x, c.y), fmaxf(c.z, c.w)));
    st += c.x + c.y + c.z + c.w;
  }
  for (int off = 32; off > 0; off >>= 1) {
    mnp = fminf(mnp, __shfl_down(mnp, off));
    mxp = fmaxf(mxp, __shfl_down(mxp, off));
    mnt = fminf(mnt, __shfl_down(mnt, off));
    mxt = fmaxf(mxt, __shfl_down(mxt, off));
    st += __shfl_down(st, off);
  }
  __shared__ float s_mnp[4], s_mxp[4], s_mnt[4], s_mxt[4], s_st[4];
  int wave = tid >> 6, lane = tid & 63;
  if (lane == 0) {
    s_mnp[wave] = mnp; s_mxp[wave] = mxp;
    s_mnt[wave] = mnt; s_mxt[wave] = mxt; s_st[wave] = st;
  }
  __syncthreads();
  if (tid == 0) {
    for (int w = 1; w < 4; ++w) {
      mnp = fminf(mnp, s_mnp[w]); mxp = fmaxf(mxp, s_mxp[w]);
      mnt = fminf(mnt, s_mnt[w]); mxt = fmaxf(mxt, s_mxt[w]);
      st += s_st[w];
    }
    wsf[P_MINP + blockIdx.x] = mnp;
    wsf[P_MAXP + blockIdx.x] = mxp;
    wsf[P_MINT + blockIdx.x] = mnt;
    wsf[P_MAXT + blockIdx.x] = mxt;
    wsf[P_SUMT + blockIdx.x] = st;
    if (blockIdx.x == 0) {
      wsf[WS_S] = 0.f;
      ((unsigned int*)wsf)[WS_CNT] = 0u;
    }
  }
}

// ---- Grouped-barrier SSIM: R0's proven per-row body, 6 rows per barrier ----
// Stage 6 rows (block-wide, full 256 cols) into parity-alternating buffers,
// ONE __syncthreads, then 6 h-conv + v-conv bodies. Barriers: 42 -> 7.
// WAR safe: group g+1 writes parity^1; reads of parity p (group g) are
// consumed before any wave reaches barrier g+1, and writes to parity p
// resume only after barrier g+1.

#define ROW_STORE(JJ, GP, R, TC, PC) do {                                    \
    constexpr int jj = (JJ);                                                 \
    const bool in = (unsigned)(ystart + jj) < (unsigned)HH;                  \
    v2f nv;                                                                  \
    nv.x = in ? fmaf(TC, ts, tb) : 0.f;                                      \
    nv.y = in ? fmaf(PC, ps, pb) : 0.f;                                      \
    srow[GP][R][x + 5] = nv;                                                 \
  } while (0)

#define PREF(JJ, TN, PN) do {                                                \
    const int yn = min(max(ystart + (JJ), 0), HH - 1);                       \
    TN = tptr[(size_t)yn * WW + x];                                          \
    PN = pptr[(size_t)yn * WW + x];                                          \
  } while (0)

#define ROW_COMP(JJ, GP, R) do {                                             \
    constexpr int jj = (JJ);                                                 \
    constexpr int slot = jj % 11;                                            \
    v2f hmu = {0.f, 0.f}, hsq = {0.f, 0.f};                                  \
    float htp = 0.f;                                                         \
    _Pragma("unroll")                                                        \
    for (int k = 0; k < 11; ++k) {                                           \
      v2f v = srow[GP][R][x + k];                                            \
      v2f g2 = {GA_(k), GA_(k)};                                             \
      v2f w = g2 * v;                                                        \
      hmu = hmu + w;                                                         \
      hsq = __builtin_elementwise_fma(w, v, hsq);                            \
      htp = fmaf(w.x, v.y, htp);                                             \
    }                                                                        \
    r_mu[slot] = hmu; r_sq[slot] = hsq; r_tp[slot] = htp;                    \
    if constexpr (jj >= 10) {                                                \
      v2f vmu = {0.f, 0.f}, vsq = {0.f, 0.f};                                \
      float vtp = 0.f;                                                       \
      _Pragma("unroll")                                                      \
      for (int k = 0; k < 11; ++k) {                                         \
        const int s = (jj + 1 + k) % 11;                                     \
        v2f g2 = {GA_(k), GA_(k)};                                           \
        vmu = __builtin_elementwise_fma(g2, r_mu[s], vmu);                   \
        vsq = __builtin_elementwise_fma(g2, r_sq[s], vsq);                   \
        vtp = fmaf(GA_(k), r_tp[s], vtp);                                    \
      }                                                                      \
      float m1 = vmu.x, m2 = vmu.y;                                          \
      float mu11 = m1 * m1, mu22 = m2 * m2, m12 = m1 * m2;                   \
      float s1 = fmaxf(vsq.x - mu11, 1e-6f);                                 \
      float s2 = fmaxf(vsq.y - mu22, 1e-6f);                                 \
      float s12 = vtp - m12;                                                 \
      float root = sqrtf(s1 * s2);                                           \
      float num = fmaf(2.f, m12, C1) * fmaf(2.f, root, C2) * (s12 + C3);     \
      float den = (mu11 + mu22 + C1) * (s1 + s2 + C2) * (root + C3);         \
      acc = fmaf(num, __builtin_amdgcn_rcpf(den), acc);                      \
    }                                                                        \
  } while (0)

#define GROUP(G) do {                                                        \
    constexpr int g = (G); constexpr int gp = g & 1;                         \
    ROW_STORE(6*g+0, gp, 0, tc0, pc0);                                       \
    ROW_STORE(6*g+1, gp, 1, tc1, pc1);                                       \
    ROW_STORE(6*g+2, gp, 2, tc2, pc2);                                       \
    ROW_STORE(6*g+3, gp, 3, tc3, pc3);                                       \
    ROW_STORE(6*g+4, gp, 4, tc4, pc4);                                       \
    ROW_STORE(6*g+5, gp, 5, tc5, pc5);                                       \
    if constexpr (g < 6) {                                                   \
      PREF(6*g+6,  tn0, pn0); PREF(6*g+7,  tn1, pn1);                        \
      PREF(6*g+8,  tn2, pn2); PREF(6*g+9,  tn3, pn3);                        \
      PREF(6*g+10, tn4, pn4); PREF(6*g+11, tn5, pn5);                        \
    }                                                                        \
    __syncthreads();                                                         \
    ROW_COMP(6*g+0, gp, 0); ROW_COMP(6*g+1, gp, 1);                          \
    ROW_COMP(6*g+2, gp, 2); ROW_COMP(6*g+3, gp, 3);                          \
    ROW_COMP(6*g+4, gp, 4); ROW_COMP(6*g+5, gp, 5);                          \
    tc0 = tn0; pc0 = pn0; tc1 = tn1; pc1 = pn1; tc2 = tn2; pc2 = pn2;        \
    tc3 = tn3; pc3 = pn3; tc4 = tn4; pc4 = pn4; tc5 = tn5; pc5 = pn5;        \
    __builtin_amdgcn_sched_barrier(0);                                       \
  } while (0)

__global__ __launch_bounds__(256, 4) void k_ssim(const float* __restrict__ pred,
                                                 const float* __restrict__ targ,
                                                 float* __restrict__ wsf,
                                                 float* __restrict__ out) {
  const int img = blockIdx.x >> 3;    // 0..127
  const int chunk = blockIdx.x & 7;   // 0..7
  const int b = img >> 4;             // sample
  const int x = threadIdx.x;
  const int y0 = chunk * CROWS;
  const float* tptr = targ + (size_t)img * (HH * WW);
  const float* pptr = pred + (size_t)img * (HH * WW);

  // Preamble: reduce this sample's 64 partials -> norm params + valid (wave 0)
  __shared__ float sprm[5];  // ps, pb, ts, tb, valid
  if (x < 64) {
    float mnp = wsf[P_MINP + b * 64 + x];
    float mxp = wsf[P_MAXP + b * 64 + x];
    float mnt = wsf[P_MINT + b * 64 + x];
    float mxt = wsf[P_MAXT + b * 64 + x];
    float st  = wsf[P_SUMT + b * 64 + x];
    for (int off = 32; off > 0; off >>= 1) {
      mnp = fminf(mnp, __shfl_down(mnp, off));
      mxp = fmaxf(mxp, __shfl_down(mxp, off));
      mnt = fminf(mnt, __shfl_down(mnt, off));
      mxt = fmaxf(mxt, __shfl_down(mxt, off));
      st += __shfl_down(st, off);
    }
    if (x == 0) {
      float psv = 1.f / fmaxf(mxp - mnp, 1e-6f);
      float tsv = 1.f / fmaxf(mxt - mnt, 1e-6f);
      sprm[0] = psv; sprm[1] = -mnp * psv;
      sprm[2] = tsv; sprm[3] = -mnt * tsv;
      sprm[4] = (st != 0.f) ? 1.f : 0.f;
    }
  }

  // Staging: 2 parities x 6 rows of (t,p) float2, 5-wide zero halos. ~25.7KB.
  __shared__ v2f srow[2][6][WW + 12];
  if (x < 5) {
    v2f z = {0.f, 0.f};
#pragma unroll
    for (int gg = 0; gg < 2; ++gg)
#pragma unroll
      for (int rr = 0; rr < 6; ++rr) {
        srow[gg][rr][x] = z;
        srow[gg][rr][WW + 5 + x] = z;
      }
  }
  __syncthreads();
  const float ps = sprm[0], pb = sprm[1], ts = sprm[2], tb = sprm[3];

  // Ring: h-conv results for 11 rows; only constant indices -> registers.
  v2f r_mu[11], r_sq[11];
  float r_tp[11];
  float acc = 0.f;
  const int ystart = y0 - 5;  // row jj stages image row ystart+jj
  const float C1 = 1e-4f, C2 = 9e-4f, C3 = 4.5e-4f;

  // Current-group and next-group register files (named scalars only).
  float tc0, pc0, tc1, pc1, tc2, pc2, tc3, pc3, tc4, pc4, tc5, pc5;
  float tn0 = 0.f, pn0 = 0.f, tn1 = 0.f, pn1 = 0.f, tn2 = 0.f, pn2 = 0.f;
  float tn3 = 0.f, pn3 = 0.f, tn4 = 0.f, pn4 = 0.f, tn5 = 0.f, pn5 = 0.f;

  // Prime group 0
  PREF(0, tc0, pc0); PREF(1, tc1, pc1); PREF(2, tc2, pc2);
  PREF(3, tc3, pc3); PREF(4, tc4, pc4); PREF(5, tc5, pc5);

  GROUP(0); GROUP(1); GROUP(2); GROUP(3); GROUP(4); GROUP(5); GROUP(6);

  // Block reduction + valid-weighted accumulate + ticket
  for (int off = 32; off > 0; off >>= 1) acc += __shfl_down(acc, off);
  __shared__ float sred[4];
  __shared__ unsigned int s_last;
  if ((x & 63) == 0) sred[x >> 6] = acc;
  __syncthreads();
  if (x == 0) {
    float v = sred[0] + sred[1] + sred[2] + sred[3];
    atomicAdd(&wsf[WS_S], v * sprm[4]);
    __threadfence();  // release: WS_S add visible before ticket bump
    unsigned int old = atomicAdd(((unsigned int*)wsf) + WS_CNT, 1u);
    s_last = (old == (unsigned int)(NBLK - 1)) ? 1u : 0u;
  }
  __syncthreads();

  // Loss epilogue: exactly one block (the last to tick) computes out[0].
  if (s_last && x < 64) {
    float sums[8];
#pragma unroll
    for (int bb = 0; bb < 8; ++bb) sums[bb] = wsf[P_SUMT + bb * 64 + x];
    for (int off = 32; off > 0; off >>= 1) {
#pragma unroll
      for (int bb = 0; bb < 8; ++bb) sums[bb] += __shfl_down(sums[bb], off);
    }
    if (x == 0) {
      __threadfence();  // acquire side of the ticket
      float sv = 0.f;
#pragma unroll
      for (int bb = 0; bb < 8; ++bb) sv += (sums[bb] != 0.f) ? 1.f : 0.f;
      float S = atomicAdd(&wsf[WS_S], 0.f);  // coherent read of final sum
      out[0] = (sv - S * (1.f / (float)NPX)) / fmaxf(sv, 1.f);
    }
  }
}

extern "C" void kernel_launch(void* const* d_in, const int* in_sizes, int n_in,
                              void* d_out, int out_size, void* d_ws, size_t ws_size,
                              hipStream_t stream) {
  const float* pred = (const float*)d_in[0];
  const float* targ = (const float*)d_in[1];
  float* wsf = (float*)d_ws;
  float* out = (float*)d_out;

  hipLaunchKernelGGL(k_reduce, dim3(512), dim3(256), 0, stream, pred, targ, wsf);
  hipLaunchKernelGGL(k_ssim, dim3(NBLK), dim3(256), 0, stream, pred, targ, wsf, out);
}